// Round 4
// baseline (330.239 us; speedup 1.0000x reference)
//
#include <hip/hip_runtime.h>
#include <math.h>

#define IN_DIM 128
#define OUT_DIM 64
#define NEG_SLOPE 0.01f

// ---------------- init: count=0 ----------------
__global__ void init_kernel(int* __restrict__ count, int N) {
  int i = blockIdx.x * blockDim.x + threadIdx.x;
  if (i < N) count[i] = 0;
}

// ---------------- fc: z = h @ W ; s = z@a_l ; t = z@a_r ----------------
// 64 nodes/block, 4 waves, wave=16 nodes, lane=output column.
// Only the h-tile lives in LDS (32 KiB -> 5 blocks/CU, ~62% occupancy).
// W is 32 KB total and shared by all blocks -> L1/L2-hot, read directly
// from global per k-quad (coalesced, reused over 16 rows).
__global__ __launch_bounds__(256) void fc_kernel(
    const float* __restrict__ h, const float* __restrict__ W,
    const float* __restrict__ al, const float* __restrict__ ar,
    float* __restrict__ z, float* __restrict__ s, float* __restrict__ t, int N) {
  __shared__ float hlds[64][IN_DIM];  // 32 KiB
  int tid = threadIdx.x;
  int nb = blockIdx.x * 64;

  for (int it = tid; it < 64 * (IN_DIM / 4); it += 256) {
    int r = it >> 5;
    int kq = it & 31;
    int row = nb + r;
    float4 v = make_float4(0.f, 0.f, 0.f, 0.f);
    if (row < N) v = *(const float4*)&h[(size_t)row * IN_DIM + kq * 4];
    *(float4*)&hlds[r][kq * 4] = v;
  }
  __syncthreads();

  int lane = tid & 63, wid = tid >> 6;
  int n0 = wid * 16;
  float acc[16];
#pragma unroll
  for (int i = 0; i < 16; ++i) acc[i] = 0.f;

  for (int kq = 0; kq < IN_DIM / 4; ++kq) {
    int k = kq * 4;
    float w0 = W[(size_t)(k + 0) * OUT_DIM + lane];  // L1-hot, coalesced
    float w1 = W[(size_t)(k + 1) * OUT_DIM + lane];
    float w2 = W[(size_t)(k + 2) * OUT_DIM + lane];
    float w3 = W[(size_t)(k + 3) * OUT_DIM + lane];
#pragma unroll
    for (int nn = 0; nn < 16; ++nn) {
      float4 hv = *(const float4*)&hlds[n0 + nn][k];  // wave-uniform broadcast
      float a = acc[nn];
      a = fmaf(hv.x, w0, a);
      a = fmaf(hv.y, w1, a);
      a = fmaf(hv.z, w2, a);
      a = fmaf(hv.w, w3, a);
      acc[nn] = a;
    }
  }

  float alv = al[lane], arv = ar[lane];
#pragma unroll
  for (int nn = 0; nn < 16; ++nn) {
    int row = nb + n0 + nn;
    float p = acc[nn] * alv;
    float q = acc[nn] * arv;
#pragma unroll
    for (int off = 32; off; off >>= 1) {
      p += __shfl_down(p, off);
      q += __shfl_down(q, off);
    }
    if (row < N) {
      z[(size_t)row * OUT_DIM + lane] = acc[nn];
      if (lane == 0) { s[row] = p; t[row] = q; }
    }
  }
}

// ---------------- edge pass 1: degree count + rank assignment ----------------
__global__ void edge_pass1(const int* __restrict__ dst, int* __restrict__ count,
                           int* __restrict__ rank, int E) {
  int i = blockIdx.x * blockDim.x + threadIdx.x;
  if (i < E) rank[i] = atomicAdd(&count[dst[i]], 1);
}

// ---------------- CSR build ----------------
__global__ __launch_bounds__(256) void scan_block_sums(const int* __restrict__ count, int N,
                                                       int* __restrict__ bsums) {
  int b = blockIdx.x, tid = threadIdx.x;
  int base = b * 2048;
  int sum = 0;
  for (int i = tid; i < 2048; i += 256) {
    int idx = base + i;
    if (idx < N) sum += count[idx];
  }
#pragma unroll
  for (int off = 32; off; off >>= 1) sum += __shfl_down(sum, off);
  __shared__ int ws[4];
  int lane = tid & 63, wid = tid >> 6;
  if (lane == 0) ws[wid] = sum;
  __syncthreads();
  if (tid == 0) bsums[b] = ws[0] + ws[1] + ws[2] + ws[3];
}

__global__ void scan_bsums(const int* __restrict__ bsums, int nb, int* __restrict__ bofs,
                           int* __restrict__ offs, int N, int E) {
  if (blockIdx.x == 0 && threadIdx.x == 0) {
    int run = 0;
    for (int i = 0; i < nb; ++i) { bofs[i] = run; run += bsums[i]; }
    offs[N] = E;
  }
}

__global__ __launch_bounds__(256) void scan_write(const int* __restrict__ count, int N,
                                                  const int* __restrict__ bofs,
                                                  int* __restrict__ offs) {
  int b = blockIdx.x, tid = threadIdx.x;
  int base = b * 2048 + tid * 8;
  int v[8];
  int tot = 0;
#pragma unroll
  for (int i = 0; i < 8; ++i) {
    int idx = base + i;
    int c = (idx < N) ? count[idx] : 0;
    v[i] = c;
    tot += c;
  }
  int lane = tid & 63, wid = tid >> 6;
  int x = tot;
#pragma unroll
  for (int off = 1; off < 64; off <<= 1) {
    int y = __shfl_up(x, off);
    if (lane >= off) x += y;
  }
  __shared__ int wtot[4];
  if (lane == 63) wtot[wid] = x;
  __syncthreads();
  int wbase = 0;
  for (int w2 = 0; w2 < wid; ++w2) wbase += wtot[w2];
  int run = bofs[b] + wbase + (x - tot);
#pragma unroll
  for (int i = 0; i < 8; ++i) {
    int idx = base + i;
    if (idx < N) offs[idx] = run;
    run += v[i];
  }
}

// ---------------- edge pass 2: scatter src into CSR order (no atomics) ----------------
__global__ void edge_pass2(const int* __restrict__ src, const int* __restrict__ dst,
                           const int* __restrict__ rank, const int* __restrict__ offs,
                           int* __restrict__ csr_src, int E) {
  int i = blockIdx.x * blockDim.x + threadIdx.x;
  if (i >= E) return;
  int d = dst[i];
  csr_src[offs[d] + rank[i]] = src[i];
}

// ---------------- aggregate: wave per node ----------------
__global__ __launch_bounds__(256) void aggregate_kernel(
    const int* __restrict__ offs, const int* __restrict__ csr_src,
    const float* __restrict__ s, const float* __restrict__ t,
    const float* __restrict__ z, float* __restrict__ out, int N) {
  int wid = threadIdx.x >> 6, lane = threadIdx.x & 63;
  int n = blockIdx.x * 4 + wid;
  if (n >= N) return;
  int beg = offs[n], end = offs[n + 1];
  int deg = end - beg;
  float acc = 0.f;

  if (deg > 0 && deg <= 64) {
    float tn = t[n];
    float e_l = -INFINITY;
    int sn_l = 0;
    if (lane < deg) {
      sn_l = csr_src[beg + lane];
      float e = s[sn_l] + tn;
      e_l = e > 0.f ? e : NEG_SLOPE * e;
    }
    float mn = e_l;
#pragma unroll
    for (int off = 32; off; off >>= 1) mn = fmaxf(mn, __shfl_xor(mn, off));
    float w_l = (lane < deg) ? __expf(e_l - mn) : 0.f;
    float wsum = w_l;
#pragma unroll
    for (int off = 32; off; off >>= 1) wsum += __shfl_xor(wsum, off);
    int k = 0;
    for (; k + 4 <= deg; k += 4) {
      int s0 = __shfl(sn_l, k + 0), s1 = __shfl(sn_l, k + 1);
      int s2 = __shfl(sn_l, k + 2), s3 = __shfl(sn_l, k + 3);
      float w0 = __shfl(w_l, k + 0), w1 = __shfl(w_l, k + 1);
      float w2 = __shfl(w_l, k + 2), w3 = __shfl(w_l, k + 3);
      float z0 = z[(size_t)s0 * OUT_DIM + lane];
      float z1 = z[(size_t)s1 * OUT_DIM + lane];
      float z2 = z[(size_t)s2 * OUT_DIM + lane];
      float z3 = z[(size_t)s3 * OUT_DIM + lane];
      acc = fmaf(w0, z0, acc);
      acc = fmaf(w1, z1, acc);
      acc = fmaf(w2, z2, acc);
      acc = fmaf(w3, z3, acc);
    }
    for (; k < deg; ++k) {
      int s0 = __shfl(sn_l, k);
      float w0 = __shfl(w_l, k);
      acc = fmaf(w0, z[(size_t)s0 * OUT_DIM + lane], acc);
    }
    acc /= wsum;
  } else if (deg > 64) {
    float tn = t[n];
    float mn = -INFINITY;
    for (int p = beg + lane; p < end; p += 64) {
      float e = s[csr_src[p]] + tn;
      e = e > 0.f ? e : NEG_SLOPE * e;
      mn = fmaxf(mn, e);
    }
#pragma unroll
    for (int off = 32; off; off >>= 1) mn = fmaxf(mn, __shfl_xor(mn, off));
    float wsum = 0.f;
    for (int p = beg; p < end; ++p) {
      int sn = csr_src[p];
      float e = s[sn] + tn;
      e = e > 0.f ? e : NEG_SLOPE * e;
      float w = __expf(e - mn);
      wsum += w;
      acc = fmaf(w, z[(size_t)sn * OUT_DIM + lane], acc);
    }
    acc /= wsum;
  }
  out[(size_t)n * OUT_DIM + lane] = acc;
}

extern "C" void kernel_launch(void* const* d_in, const int* in_sizes, int n_in,
                              void* d_out, int out_size, void* d_ws, size_t ws_size,
                              hipStream_t stream) {
  const float* h = (const float*)d_in[0];
  const int* src = (const int*)d_in[1];
  const int* dst = (const int*)d_in[2];
  const float* W = (const float*)d_in[3];
  const float* al = (const float*)d_in[4];
  const float* ar = (const float*)d_in[5];
  float* out = (float*)d_out;
  int N = in_sizes[0] / IN_DIM;
  int E = in_sizes[1];

  // workspace layout (all written before read every call)
  float* z = (float*)d_ws;                 // N*64
  float* s = z + (size_t)N * OUT_DIM;      // N
  float* t = s + N;                        // N
  int* count = (int*)(t + N);              // N
  int* offs = count + N;                   // N+1
  int* rank = offs + N + 1;                // E
  int* csr_src = rank + E;                 // E
  int* bsums = csr_src + E;                // <=256
  int* bofs = bsums + 256;                 // <=256

  const int NB = (N + 2047) / 2048;

  hipLaunchKernelGGL(init_kernel, dim3((N + 255) / 256), dim3(256), 0, stream, count, N);
  hipLaunchKernelGGL(fc_kernel, dim3((N + 63) / 64), dim3(256), 0, stream, h, W, al, ar, z, s, t, N);
  hipLaunchKernelGGL(edge_pass1, dim3((E + 255) / 256), dim3(256), 0, stream, dst, count, rank, E);
  hipLaunchKernelGGL(scan_block_sums, dim3(NB), dim3(256), 0, stream, count, N, bsums);
  hipLaunchKernelGGL(scan_bsums, dim3(1), dim3(64), 0, stream, bsums, NB, bofs, offs, N, E);
  hipLaunchKernelGGL(scan_write, dim3(NB), dim3(256), 0, stream, count, N, bofs, offs);
  hipLaunchKernelGGL(edge_pass2, dim3((E + 255) / 256), dim3(256), 0, stream, src, dst, rank, offs, csr_src, E);
  hipLaunchKernelGGL(aggregate_kernel, dim3((N + 3) / 4), dim3(256), 0, stream, offs, csr_src, s, t, z, out, N);
}